// Round 1
// baseline (328.811 us; speedup 1.0000x reference)
//
#include <hip/hip_runtime.h>
#include <stdint.h>

typedef unsigned long long u64;

#define N_ 128
#define C_ 256
#define H_ 28
#define W_ 28
#define BN_EPS_ 1e-5f

// ---------------------------------------------------------------------------
// Kernel 1: bit-pack activations. One block per (n, h).
// Phase 1: coalesced float4 staging of the C x W slab into LDS (stride 29 pad).
// Phase 2: wave k ballots word k; lane = channel-within-word reads LDS
// (29*lane mod 32 covers all banks -> 2 lanes/bank = conflict-free).
// xbits layout: [n][h][w][4] u64; bit c&63 of word c>>6 = (x[n,c,h,w] < 0).
// ---------------------------------------------------------------------------
__global__ __launch_bounds__(256) void pack_x_kernel(const float* __restrict__ x,
                                                     u64* __restrict__ xbits) {
    int nh = blockIdx.x;            // n*H + h
    int h  = nh % H_;
    int n  = nh / H_;
    __shared__ float sx[C_][W_ + 1];   // 256*29*4 = 29696 B

    const float* xplane = x + ((size_t)n * C_ * H_ + h) * W_;  // + c*H*W + w
    // 7 float4 per channel, 1792 vec-loads over 256 threads (7 iters).
    for (int i = threadIdx.x; i < C_ * 7; i += 256) {
        int c = i / 7, q = i - c * 7;
        float4 v = *(const float4*)(xplane + (size_t)c * (H_ * W_) + q * 4);
        sx[c][q * 4 + 0] = v.x;
        sx[c][q * 4 + 1] = v.y;
        sx[c][q * 4 + 2] = v.z;
        sx[c][q * 4 + 3] = v.w;
    }
    __syncthreads();

    int k    = threadIdx.x >> 6;    // word index (wave id)
    int lane = threadIdx.x & 63;
    int c    = k * 64 + lane;
    u64 my = 0;
    #pragma unroll
    for (int w = 0; w < W_; ++w) {
        u64 mask = __ballot(sx[c][w] < 0.f);
        if (lane == w) my = mask;
    }
    if (lane < W_) xbits[((size_t)nh * W_ + lane) * 4 + k] = my;
}

// ---------------------------------------------------------------------------
// Kernel 2: bit-pack weights via wave ballot. wbits layout: [co][tap(9)][4].
// ---------------------------------------------------------------------------
__global__ __launch_bounds__(256) void pack_w_kernel(const float* __restrict__ w,
                                                     u64* __restrict__ wbits) {
    int gid  = blockIdx.x * blockDim.x + threadIdx.x;
    int wave = gid >> 6;
    int lane = gid & 63;
    if (wave >= C_ * 9 * 4) return;
    int k    = wave & 3;
    int rest = wave >> 2;     // co*9 + tap
    int tap  = rest % 9;
    int co   = rest / 9;
    int ci   = k * 64 + lane;
    float val = w[((size_t)co * C_ + ci) * 9 + tap];
    u64 mask = __ballot(val < 0.f);
    if (lane == 0) wbits[wave] = mask;
}

// ---------------------------------------------------------------------------
// Kernel 3: binarized conv + BN + hardtanh + residual.
// Block = (n, h); thread = co. Sliding-window column pipeline along w.
// Changes vs prior version:
//   * __launch_bounds__(256, 2): register budget 256 VGPRs so the 72-VGPR
//     weight fragment array stays resident (was spilling at VGPR_Count=64).
//   * sacc[28] eliminated: out(iw-1) is final at iteration iw, so BN+clip+
//     sout write is fused into the loop. lx and sout are now separate LDS
//     buffers (32384 B total, still 4 blocks/CU).
// ---------------------------------------------------------------------------
__global__ __launch_bounds__(256, 2) void conv_kernel(
    const u64* __restrict__ xbits, const u64* __restrict__ wbits,
    const float* __restrict__ x,
    const float* __restrict__ gamma, const float* __restrict__ beta,
    const float* __restrict__ mean, const float* __restrict__ var,
    float* __restrict__ out) {
    int nh = blockIdx.x;
    int h  = nh % H_;
    int n  = nh / H_;
    int co = threadIdx.x;

    __shared__ u64   lx[3][W_][4];       // 2688 B
    __shared__ float sout[C_][W_ + 1];   // 29696 B, stride-29 padded

    float inv  = gamma[co] / sqrtf(var[co] + BN_EPS_);
    float bias = beta[co] - mean[co] * inv;

    // Per-thread weight fragments: 9 taps x 4 u64 = 72 VGPRs (resident).
    u64 wr[9][4];
    {
        const ulonglong2* wp = (const ulonglong2*)wbits + (size_t)co * 18;
        #pragma unroll
        for (int i = 0; i < 9; ++i) {
            ulonglong2 a = wp[i * 2];
            ulonglong2 b = wp[i * 2 + 1];
            wr[i][0] = a.x; wr[i][1] = a.y; wr[i][2] = b.x; wr[i][3] = b.y;
        }
    }

    // Stage 3 input bit-rows (336 u64) into LDS, coalesced.
    for (int i = threadIdx.x; i < 3 * W_ * 4; i += 256) {
        int k    = i & 3;
        int rest = i >> 2;
        int ww   = rest % W_;
        int r    = rest / W_;
        int ih   = h - 1 + r;
        u64 v = 0;
        if (ih >= 0 && ih < H_)
            v = xbits[(((size_t)n * H_ + ih) * W_ + ww) * 4 + k];
        lx[r][ww][k] = v;
    }
    __syncthreads();

    const bool row0 = (h > 0);
    const bool row2 = (h < H_ - 1);
    const int  nrows = 1 + (row0 ? 1 : 0) + (row2 ? 1 : 0);
    const int  nv3 = C_ * nrows * 3;   // interior columns
    const int  nv2 = C_ * nrows * 2;   // edge columns (w==0, w==W-1)

    int pm = 0, pc = 0;

    for (int iw = 0; iw < W_; ++iw) {
        int a0 = 0, a1 = 0, a2 = 0;
        u64 xw0, xw1, xw2, xw3;
        #define TAPROW(r, wb)                                                  \
            xw0 = lx[r][iw][0]; xw1 = lx[r][iw][1];                            \
            xw2 = lx[r][iw][2]; xw3 = lx[r][iw][3];                            \
            a0 += __popcll(xw0 ^ wr[wb+0][0]) + __popcll(xw1 ^ wr[wb+0][1]) +  \
                  __popcll(xw2 ^ wr[wb+0][2]) + __popcll(xw3 ^ wr[wb+0][3]);   \
            a1 += __popcll(xw0 ^ wr[wb+1][0]) + __popcll(xw1 ^ wr[wb+1][1]) +  \
                  __popcll(xw2 ^ wr[wb+1][2]) + __popcll(xw3 ^ wr[wb+1][3]);   \
            a2 += __popcll(xw0 ^ wr[wb+2][0]) + __popcll(xw1 ^ wr[wb+2][1]) +  \
                  __popcll(xw2 ^ wr[wb+2][2]) + __popcll(xw3 ^ wr[wb+2][3]);
        if (row0) { TAPROW(0, 0) }
        { TAPROW(1, 3) }
        if (row2) { TAPROW(2, 6) }
        #undef TAPROW

        // out(iw-1) is complete: fuse BN + hardtanh + LDS-transpose write.
        if (iw >= 1) {
            int s  = pm + a2;
            int nv = (iw == 1) ? nv2 : nv3;   // ow==0 has 2 columns
            float val = (float)(nv - 2 * s) * inv + bias;
            val = fminf(1.f, fmaxf(-1.f, val));
            sout[co][iw - 1] = val;
        }
        pm = pc + a1;
        pc = a0;
    }
    {   // ow == W-1: 2 columns
        float val = (float)(nv2 - 2 * pm) * inv + bias;
        val = fminf(1.f, fmaxf(-1.f, val));
        sout[co][W_ - 1] = val;
    }
    __syncthreads();

    // Coalesced residual add + store: contiguous 112B per (c) run.
    const float* xplane = x   + ((size_t)n * C_ * H_ + h) * W_;
    float*       oplane = out + ((size_t)n * C_ * H_ + h) * W_;
    for (int i = threadIdx.x; i < C_ * W_; i += 256) {
        int c    = i / W_;
        int wpos = i - c * W_;
        size_t g = (size_t)c * (H_ * W_) + wpos;
        oplane[g] = sout[c][wpos] + xplane[g];
    }
}

// ---------------------------------------------------------------------------
extern "C" void kernel_launch(void* const* d_in, const int* in_sizes, int n_in,
                              void* d_out, int out_size, void* d_ws, size_t ws_size,
                              hipStream_t stream) {
    const float* x     = (const float*)d_in[0];
    const float* w     = (const float*)d_in[1];
    const float* gamma = (const float*)d_in[2];
    const float* beta  = (const float*)d_in[3];
    const float* mean  = (const float*)d_in[4];
    const float* var   = (const float*)d_in[5];
    float* out = (float*)d_out;

    u64* xbits = (u64*)d_ws;                                 // 128*28*28*4 u64 = 3.21 MB
    u64* wbits = xbits + (size_t)N_ * H_ * W_ * 4;           // 256*9*4 u64 = 72 KB

    pack_x_kernel<<<N_ * H_, 256, 0, stream>>>(x, xbits);
    pack_w_kernel<<<(C_ * 9 * 4 * 64) / 256, 256, 0, stream>>>(w, wbits);
    conv_kernel<<<N_ * H_, 256, 0, stream>>>(xbits, wbits, x, gamma, beta, mean, var, out);
}

// Round 3
// 320.709 us; speedup vs baseline: 1.0253x; 1.0253x over previous
//
#include <hip/hip_runtime.h>
#include <stdint.h>

typedef unsigned long long u64;

#define N_ 128
#define C_ 256
#define H_ 28
#define W_ 28
#define BN_EPS_ 1e-5f

// Round 3 = round 2 resubmission: round-2 bench failed on container infra
// ("MI355X container failed twice"), no counters produced. Source audited
// for hangs/illegal config; none found.

// ---------------------------------------------------------------------------
// Kernel 1: bit-pack activations. One block per (n, h).
// Phase 1: coalesced float4 staging of the C x W slab into LDS (stride 29 pad).
// Phase 2: wave k ballots word k; lane = channel-within-word reads LDS
// (29*lane mod 32 covers all banks -> 2 lanes/bank = conflict-free).
// xbits layout: [n][h][w][4] u64; bit c&63 of word c>>6 = (x[n,c,h,w] < 0).
// ---------------------------------------------------------------------------
__global__ __launch_bounds__(256) void pack_x_kernel(const float* __restrict__ x,
                                                     u64* __restrict__ xbits) {
    int nh = blockIdx.x;            // n*H + h
    int h  = nh % H_;
    int n  = nh / H_;
    __shared__ float sx[C_][W_ + 1];   // 256*29*4 = 29696 B

    const float* xplane = x + ((size_t)n * C_ * H_ + h) * W_;  // + c*H*W + w
    for (int i = threadIdx.x; i < C_ * 7; i += 256) {
        int c = i / 7, q = i - c * 7;
        float4 v = *(const float4*)(xplane + (size_t)c * (H_ * W_) + q * 4);
        sx[c][q * 4 + 0] = v.x;
        sx[c][q * 4 + 1] = v.y;
        sx[c][q * 4 + 2] = v.z;
        sx[c][q * 4 + 3] = v.w;
    }
    __syncthreads();

    int k    = threadIdx.x >> 6;    // word index (wave id)
    int lane = threadIdx.x & 63;
    int c    = k * 64 + lane;
    u64 my = 0;
    #pragma unroll
    for (int w = 0; w < W_; ++w) {
        u64 mask = __ballot(sx[c][w] < 0.f);
        if (lane == w) my = mask;
    }
    if (lane < W_) xbits[((size_t)nh * W_ + lane) * 4 + k] = my;
}

// ---------------------------------------------------------------------------
// Kernel 2: bit-pack weights via wave ballot. wbits layout: [co][tap(9)][4].
// ---------------------------------------------------------------------------
__global__ __launch_bounds__(256) void pack_w_kernel(const float* __restrict__ w,
                                                     u64* __restrict__ wbits) {
    int gid  = blockIdx.x * blockDim.x + threadIdx.x;
    int wave = gid >> 6;
    int lane = gid & 63;
    if (wave >= C_ * 9 * 4) return;
    int k    = wave & 3;
    int rest = wave >> 2;     // co*9 + tap
    int tap  = rest % 9;
    int co   = rest / 9;
    int ci   = k * 64 + lane;
    float val = w[((size_t)co * C_ + ci) * 9 + tap];
    u64 mask = __ballot(val < 0.f);
    if (lane == 0) wbits[wave] = mask;
}

// ---------------------------------------------------------------------------
// Kernel 3: binarized conv + BN + hardtanh + residual.
// Block = (n, h), 512 threads; thread = (co, half). Each thread owns HALF the
// input-channel words (2 of 4 u64), so the weight fragment array is only
// wr[9][2] = 36 VGPRs -- small enough to provably stay register-resident
// (round-1 evidence: 72-VGPR fragments were AGPR-parked / shuffled at
// VGPR_Count=48, inflating VALU ops 2.7x over the popcount floor).
// Partner threads are adjacent lanes of the same wave; partial sums combine
// with one __shfl_xor(s,1) per output column. Each tap-row x-fragment is a
// single ds_read_b128 (3 LDS reads/iw, was 12).
// ---------------------------------------------------------------------------
__global__ __launch_bounds__(512, 4) void conv_kernel(
    const u64* __restrict__ xbits, const u64* __restrict__ wbits,
    const float* __restrict__ x,
    const float* __restrict__ gamma, const float* __restrict__ beta,
    const float* __restrict__ mean, const float* __restrict__ var,
    float* __restrict__ out) {
    int nh = blockIdx.x;
    int h  = nh % H_;
    int n  = nh / H_;
    int co = threadIdx.x >> 1;
    int kh = threadIdx.x & 1;        // which half: u64 words {2*kh, 2*kh+1}

    __shared__ u64   lx[3][W_][4];       // 2688 B
    __shared__ float sout[C_][W_ + 1];   // 29696 B, stride-29 padded

    float inv  = gamma[co] / sqrtf(var[co] + BN_EPS_);
    float bias = beta[co] - mean[co] * inv;

    // Per-thread weight fragments: 9 taps x 2 u64 = 36 VGPRs.
    u64 wr[9][2];
    {
        const u64* wp = wbits + (size_t)co * 36 + kh * 2;
        #pragma unroll
        for (int t = 0; t < 9; ++t) {
            ulonglong2 a = *(const ulonglong2*)(wp + t * 4);
            wr[t][0] = a.x; wr[t][1] = a.y;
        }
    }

    // Stage 3 input bit-rows (336 u64) into LDS, coalesced (one per thread).
    if (threadIdx.x < 3 * W_ * 4) {
        int i    = threadIdx.x;
        int k    = i & 3;
        int rest = i >> 2;
        int ww   = rest % W_;
        int r    = rest / W_;
        int ih   = h - 1 + r;
        u64 v = 0;
        if (ih >= 0 && ih < H_)
            v = xbits[(((size_t)n * H_ + ih) * W_ + ww) * 4 + k];
        lx[r][ww][k] = v;
    }
    __syncthreads();

    const bool row0 = (h > 0);
    const bool row2 = (h < H_ - 1);
    const int  nrows = 1 + (row0 ? 1 : 0) + (row2 ? 1 : 0);
    const int  nv3 = C_ * nrows * 3;   // interior columns
    const int  nv2 = C_ * nrows * 2;   // edge columns (w==0, w==W-1)

    int pm = 0, pc = 0;

    #pragma unroll 4
    for (int iw = 0; iw < W_; ++iw) {
        int a0 = 0, a1 = 0, a2 = 0;
        ulonglong2 xr;
        #define TAPROW(r, wb)                                                  \
            xr = *(const ulonglong2*)&lx[r][iw][kh * 2];                       \
            a0 += __popcll(xr.x ^ wr[wb+0][0]) + __popcll(xr.y ^ wr[wb+0][1]); \
            a1 += __popcll(xr.x ^ wr[wb+1][0]) + __popcll(xr.y ^ wr[wb+1][1]); \
            a2 += __popcll(xr.x ^ wr[wb+2][0]) + __popcll(xr.y ^ wr[wb+2][1]);
        if (row0) { TAPROW(0, 0) }
        { TAPROW(1, 3) }
        if (row2) { TAPROW(2, 6) }
        #undef TAPROW

        // out(iw-1) complete: combine halves, BN + hardtanh, transpose write.
        if (iw >= 1) {
            int s = pm + a2;
            s += __shfl_xor(s, 1);
            int nv = (iw == 1) ? nv2 : nv3;
            float val = (float)(nv - 2 * s) * inv + bias;
            val = fminf(1.f, fmaxf(-1.f, val));
            if (kh == 0) sout[co][iw - 1] = val;
        }
        pm = pc + a1;
        pc = a0;
    }
    {   // ow == W-1
        int s = pm;
        s += __shfl_xor(s, 1);
        float val = (float)(nv2 - 2 * s) * inv + bias;
        val = fminf(1.f, fmaxf(-1.f, val));
        if (kh == 0) sout[co][W_ - 1] = val;
    }
    __syncthreads();

    // Coalesced residual add + store, float4 (7 vec per channel, 7 iters).
    const float* xplane = x   + ((size_t)n * C_ * H_ + h) * W_;
    float*       oplane = out + ((size_t)n * C_ * H_ + h) * W_;
    for (int i = threadIdx.x; i < C_ * 7; i += 512) {
        int c = i / 7, q = i - c * 7;
        size_t g = (size_t)c * (H_ * W_) + q * 4;
        float4 r = *(const float4*)(xplane + g);
        float4 o;
        o.x = sout[c][q * 4 + 0] + r.x;
        o.y = sout[c][q * 4 + 1] + r.y;
        o.z = sout[c][q * 4 + 2] + r.z;
        o.w = sout[c][q * 4 + 3] + r.w;
        *(float4*)(oplane + g) = o;
    }
}

// ---------------------------------------------------------------------------
extern "C" void kernel_launch(void* const* d_in, const int* in_sizes, int n_in,
                              void* d_out, int out_size, void* d_ws, size_t ws_size,
                              hipStream_t stream) {
    const float* x     = (const float*)d_in[0];
    const float* w     = (const float*)d_in[1];
    const float* gamma = (const float*)d_in[2];
    const float* beta  = (const float*)d_in[3];
    const float* mean  = (const float*)d_in[4];
    const float* var   = (const float*)d_in[5];
    float* out = (float*)d_out;

    u64* xbits = (u64*)d_ws;                                 // 128*28*28*4 u64 = 3.21 MB
    u64* wbits = xbits + (size_t)N_ * H_ * W_ * 4;           // 256*9*4 u64 = 72 KB

    pack_x_kernel<<<N_ * H_, 256, 0, stream>>>(x, xbits);
    pack_w_kernel<<<(C_ * 9 * 4 * 64) / 256, 256, 0, stream>>>(w, wbits);
    conv_kernel<<<N_ * H_, 512, 0, stream>>>(xbits, wbits, x, gamma, beta, mean, var, out);
}